// Round 5
// baseline (169.647 us; speedup 1.0000x reference)
//
#include <hip/hip_runtime.h>

typedef __bf16 bf16_t;
typedef __bf16 bf16x8 __attribute__((ext_vector_type(8)));
typedef __bf16 bf16x4 __attribute__((ext_vector_type(4)));
typedef float f32x4 __attribute__((ext_vector_type(4)));

#define HH 96
#define WW 96
#define CC 128
#define HEADS 4
#define HD 32
#define TOK (HH * WW)      // 9216
#define PLANE (TOK * CC)   // 1179648 elements
#define KW 7
#define KK 49

// weight slab offsets (bf16 elements) inside ws
#define W_QKV 0
#define W_PROJ 49152
#define W_FC1 65536
#define W_FC2 131072
#define W_TOT 196608

// fp32 -> bf16x8 (two float4 loads + cvt)
__device__ __forceinline__ bf16x8 cvt8(const float* __restrict__ p) {
    const f32x4 a = *(const f32x4*)p;
    const f32x4 b = *(const f32x4*)(p + 4);
    bf16x8 r;
    r[0] = (bf16_t)a[0]; r[1] = (bf16_t)a[1]; r[2] = (bf16_t)a[2]; r[3] = (bf16_t)a[3];
    r[4] = (bf16_t)b[0]; r[5] = (bf16_t)b[1]; r[6] = (bf16_t)b[2]; r[7] = (bf16_t)b[3];
    return r;
}

// ---------------------------------------------------------------------------
// NT-tile MFMA strip: C[m][n] += sum_k A[m][k]*W[n][k]; A,W at tile origin.
// A-frag: lane holds A[lane&15][(lane>>4)*8+j]; B-frag: W[t*16+(lane&15)][...]
// C/D: reg r -> row (lane>>4)*4+r, col t*16+(lane&15)
// ---------------------------------------------------------------------------
template <int NT>
__device__ __forceinline__ void mmaN(const bf16_t* __restrict__ A, int lda,
                                     const bf16_t* __restrict__ W, int ldb,
                                     int K, f32x4* acc) {
    const int lane = threadIdx.x & 63;
    const bf16_t* ap = A + (lane & 15) * lda + ((lane >> 4) * 8);
    const bf16_t* bp = W + (lane & 15) * ldb + ((lane >> 4) * 8);
    for (int k0 = 0; k0 < K; k0 += 32) {
        bf16x8 a = *(const bf16x8*)(ap + k0);
#pragma unroll
        for (int t = 0; t < NT; t++) {
            bf16x8 b = *(const bf16x8*)(bp + t * 16 * ldb + k0);
            acc[t] = __builtin_amdgcn_mfma_f32_16x16x32_bf16(a, b, acc[t], 0, 0, 0);
        }
    }
}

// K0: convert the 4 fp32 weight matrices to one bf16 slab in ws.
__global__ __launch_bounds__(256) void k_cvt(const float* __restrict__ qkv_w,
                                             const float* __restrict__ proj_w,
                                             const float* __restrict__ fc1_w,
                                             const float* __restrict__ fc2_w,
                                             bf16_t* __restrict__ wb) {
    const int base = (blockIdx.x * 256 + threadIdx.x) * 4;
    const float* src;
    if (base < W_PROJ)      src = qkv_w + base;
    else if (base < W_FC1)  src = proj_w + (base - W_PROJ);
    else if (base < W_FC2)  src = fc1_w + (base - W_FC1);
    else                    src = fc2_w + (base - W_FC2);
    const f32x4 a = *(const f32x4*)src;
    bf16x4 r;
    r[0] = (bf16_t)a[0]; r[1] = (bf16_t)a[1]; r[2] = (bf16_t)a[2]; r[3] = (bf16_t)a[3];
    *(bf16x4*)(wb + base) = r;
}

// K1: qkv = x @ qkv_w.T + qkv_b. x fp32 (inline cvt); q/k/v bf16 [tok][128].
__global__ __launch_bounds__(256) void k_qkv(const float* __restrict__ x,
                                             const bf16_t* __restrict__ wb,
                                             const float* __restrict__ bias,
                                             bf16_t* __restrict__ q,
                                             bf16_t* __restrict__ k,
                                             bf16_t* __restrict__ v) {
    const int wid = blockIdx.x * 4 + (threadIdx.x >> 6);   // 3456 waves
    const int m0 = (wid / 6) * 16;
    const int n0 = (wid % 6) * 64;
    const int lane = threadIdx.x & 63;
    const float* ap = x + (m0 + (lane & 15)) * CC + ((lane >> 4) * 8);
    const bf16_t* bp = wb + (n0 + (lane & 15)) * CC + ((lane >> 4) * 8);
    f32x4 acc[4] = {};
    for (int k0 = 0; k0 < CC; k0 += 32) {
        bf16x8 a = cvt8(ap + k0);
#pragma unroll
        for (int t = 0; t < 4; t++) {
            bf16x8 b = *(const bf16x8*)(bp + t * 16 * CC + k0);
            acc[t] = __builtin_amdgcn_mfma_f32_16x16x32_bf16(a, b, acc[t], 0, 0, 0);
        }
    }
#pragma unroll
    for (int t = 0; t < 4; t++) {
        const int n = n0 + t * 16 + (lane & 15);
        const float bb = bias[n];
        const int part = n >> 7;           // 0=q 1=k 2=v
        const int c = n & 127;
        bf16_t* dst = (part == 0) ? q : (part == 1) ? k : v;
#pragma unroll
        for (int r = 0; r < 4; r++) {
            const int m = m0 + (lane >> 4) * 4 + r;
            dst[m * CC + c] = (bf16_t)(acc[t][r] + bb);
        }
    }
}

// K2: neighborhood attention, LDS-tiled. Block = 4x4 token tile (576 blocks).
// Union of the 16 clipped 7x7 windows fits a 10x10 patch. k/v patch + q rows
// staged in LDS; each wave runs 16 (token,head) tasks fully out of LDS.
#define PATCH 10
#define PSZ (PATCH * PATCH)   // 100
#define KSTR 136              // padded LDS row stride (128 + 8 bf16)
__global__ __launch_bounds__(256) void k_na2d(bf16_t* __restrict__ qo,
                                              const bf16_t* __restrict__ kg,
                                              const bf16_t* __restrict__ vg) {
    __shared__ __align__(16) bf16_t ks[PSZ * KSTR];   // 27.2 KB
    __shared__ __align__(16) bf16_t vs[PSZ * KSTR];   // 27.2 KB
    __shared__ __align__(16) bf16_t qs[16 * CC];      // 4 KB
    __shared__ float2 pk[4][52];                      // per-wave {p, koff}

    const int tid = threadIdx.x;
    const int bi = blockIdx.x / 24, bj = blockIdx.x % 24;
    const int i0 = bi * 4, j0 = bj * 4;
    const int pr0 = min(max(i0 - 3, 0), HH - PATCH);  // patch origin
    const int pc0 = min(max(j0 - 3, 0), WW - PATCH);

    // stage k/v patch: 100 rows x 16 chunks of bf16x8, both tensors
    for (int idx = tid; idx < PSZ * 16; idx += 256) {
        const int row = idx >> 4, c8 = idx & 15;
        const int pi = row / 10, pj = row % 10;
        const int g = ((pr0 + pi) * WW + (pc0 + pj)) * CC + c8 * 8;
        *(bf16x8*)(ks + row * KSTR + c8 * 8) = *(const bf16x8*)(kg + g);
        *(bf16x8*)(vs + row * KSTR + c8 * 8) = *(const bf16x8*)(vg + g);
    }
    {   // stage q rows: 16 tokens x 16 chunks
        const int row = tid >> 4, c8 = tid & 15;
        const int ti = row >> 2, tj = row & 3;
        const int g = ((i0 + ti) * WW + (j0 + tj)) * CC + c8 * 8;
        *(bf16x8*)(qs + row * CC + c8 * 8) = *(const bf16x8*)(qo + g);
    }
    __syncthreads();

    const int w = tid >> 6, lane = tid & 63;
    const int wa = lane / 7, wbq = lane % 7;   // neighbor (row, col) for this lane

    for (int t = 0; t < 16; t++) {
        const int task = w * 16 + t;
        const int tl = task >> 2;          // local token 0..15
        const int head = task & 3;
        const int i = i0 + (tl >> 2), j = j0 + (tl & 3);
        const int si = min(max(i - 3, 0), HH - KW);
        const int sj = min(max(j - 3, 0), WW - KW);
        const int lr = si - pr0, lc = sj - pc0;

        // phase 1: lane = neighbor, 32-dim dot from LDS
        float logit = -1e30f;
        int koff = 0;
        if (lane < KK) {
            const int pidx = (lr + wa) * PATCH + (lc + wbq);
            koff = pidx * KSTR + head * HD;
            const bf16x8* kp = (const bf16x8*)(ks + koff);
            const bf16x8* qp = (const bf16x8*)(qs + tl * CC + head * HD);
            float s = 0.f;
#pragma unroll
            for (int d8 = 0; d8 < 4; d8++) {
                bf16x8 qv = qp[d8];
                bf16x8 kv = kp[d8];
#pragma unroll
                for (int e = 0; e < 8; e++) s += (float)qv[e] * (float)kv[e];
            }
            logit = s * 0.17677669529663687f;   // 1/sqrt(32)
        }
        float mx = logit;
#pragma unroll
        for (int off = 32; off; off >>= 1) mx = fmaxf(mx, __shfl_xor(mx, off));
        const float p = (lane < KK) ? __expf(logit - mx) : 0.f;
        float sum = p;
#pragma unroll
        for (int off = 32; off; off >>= 1) sum += __shfl_xor(sum, off);
        const float inv = 1.f / sum;
        if (lane < KK) pk[w][lane] = make_float2(p * inv, __int_as_float(koff));

        // phase 2: lane = (dim, nb-half); 25 LDS-fed FMAs, no bpermute
        const int d = lane & 31, half = lane >> 5;
        float acc = 0.f;
#pragma unroll
        for (int nn = 0; nn < 25; nn++) {
            const int idx = half * 25 + nn;
            if (idx < KK) {
                const float2 e = pk[w][idx];
                acc += e.x * (float)vs[__float_as_int(e.y) + d];
            }
        }
        acc += __shfl_xor(acc, 32);
        if (lane < 32) qo[(i * WW + j) * CC + head * HD + d] = (bf16_t)acc;
    }
}

// K3: x0 = o @ proj_w.T + proj_b  (o bf16 in d_out; x0 bf16 -> dead k plane)
__global__ __launch_bounds__(256) void k_proj(const bf16_t* __restrict__ o,
                                              const bf16_t* __restrict__ wb,
                                              const float* __restrict__ bias,
                                              bf16_t* __restrict__ x0) {
    const int wid = blockIdx.x * 4 + (threadIdx.x >> 6);   // 1152 waves
    const int m0 = (wid / 2) * 16;
    const int n0 = (wid % 2) * 64;
    f32x4 acc[4] = {};
    mmaN<4>(o + m0 * CC, CC, wb + n0 * CC, CC, CC, acc);
    const int lane = threadIdx.x & 63;
#pragma unroll
    for (int t = 0; t < 4; t++) {
        const int n = n0 + t * 16 + (lane & 15);
        const float bb = bias[n];
#pragma unroll
        for (int r = 0; r < 4; r++) {
            const int m = m0 + (lane >> 4) * 4 + r;
            x0[m * CC + n] = (bf16_t)(acc[t][r] + bb);
        }
    }
}

// K4: fused MLP: out = gelu(x0 @ fc1_w.T + fc1_b) @ fc2_w.T + fc2_b.
// 16 rows/block; h1 [16][512] bf16 in LDS (stride 520). out is FP32.
#define H1S 520
__global__ __launch_bounds__(256) void k_mlp(const bf16_t* __restrict__ x0,
                                             const bf16_t* __restrict__ w1,
                                             const float* __restrict__ b1,
                                             const bf16_t* __restrict__ w2,
                                             const float* __restrict__ b2,
                                             float* __restrict__ out) {
    __shared__ __align__(16) bf16_t h1s[16 * H1S];
    const int wv = threadIdx.x >> 6;
    const int lane = threadIdx.x & 63;
    const int m0 = blockIdx.x * 16;

    {   // stage 1: wave wv -> h1 cols [wv*128, wv*128+128)
        f32x4 acc[8] = {};
        mmaN<8>(x0 + m0 * CC, CC, w1 + (wv * 128) * CC, CC, CC, acc);
#pragma unroll
        for (int t = 0; t < 8; t++) {
            const int n = wv * 128 + t * 16 + (lane & 15);
            const float bb = b1[n];
#pragma unroll
            for (int r = 0; r < 4; r++) {
                const int m = (lane >> 4) * 4 + r;
                const float xv = acc[t][r] + bb;
                const float g = 0.5f * xv * (1.f + erff(xv * 0.7071067811865476f));
                h1s[m * H1S + n] = (bf16_t)g;
            }
        }
    }
    __syncthreads();

    {   // stage 2: wave wv -> out cols [wv*32, wv*32+32), K=512 from LDS
        f32x4 acc[2] = {};
        mmaN<2>(h1s, H1S, w2 + (wv * 32) * (4 * CC), 4 * CC, 4 * CC, acc);
#pragma unroll
        for (int t = 0; t < 2; t++) {
            const int n = wv * 32 + t * 16 + (lane & 15);
            const float bb = b2[n];
#pragma unroll
            for (int r = 0; r < 4; r++) {
                const int m = (lane >> 4) * 4 + r;
                float xv = acc[t][r] + bb;
                xv = fminf(fmaxf(xv, -1e4f), 1e4f);   // diagnostic clamp
                out[(m0 + m) * CC + n] = xv;
            }
        }
    }
}

extern "C" void kernel_launch(void* const* d_in, const int* in_sizes, int n_in,
                              void* d_out, int out_size, void* d_ws, size_t ws_size,
                              hipStream_t stream) {
    const float* x      = (const float*)d_in[0];
    const float* qkv_w  = (const float*)d_in[1];
    const float* qkv_b  = (const float*)d_in[2];
    const float* proj_w = (const float*)d_in[3];
    const float* proj_b = (const float*)d_in[4];
    const float* fc1_w  = (const float*)d_in[5];
    const float* fc1_b  = (const float*)d_in[6];
    const float* fc2_w  = (const float*)d_in[7];
    const float* fc2_b  = (const float*)d_in[8];

    // d_out (fp32-sized, 4.5 MB) doubles as bf16 scratch for q then o; the
    // final k_mlp overwrites it with the fp32 result.
    bf16_t* qo = (bf16_t*)d_out;
    bf16_t* ws = (bf16_t*)d_ws;
    bf16_t* kb = ws;                  // [9216][128] bf16
    bf16_t* vb = ws + PLANE;          // [9216][128] bf16
    bf16_t* wb = ws + 2 * PLANE;      // 196608 bf16 weight slab
    bf16_t* x0 = kb;                  // k plane dead after attention
    // total ws: 2*PLANE + W_TOT bf16 = 4.9 MB

    k_cvt <<<192,  256, 0, stream>>>(qkv_w, proj_w, fc1_w, fc2_w, wb);
    k_qkv <<<864,  256, 0, stream>>>(x, wb + W_QKV, qkv_b, qo, kb, vb);
    k_na2d<<<576,  256, 0, stream>>>(qo, kb, vb);
    k_proj<<<288,  256, 0, stream>>>(qo, wb + W_PROJ, proj_b, x0);
    k_mlp <<<576,  256, 0, stream>>>(x0, wb + W_FC1, fc1_b, wb + W_FC2, fc2_b,
                                     (float*)d_out);
}

// Round 6
// 130.856 us; speedup vs baseline: 1.2964x; 1.2964x over previous
//
#include <hip/hip_runtime.h>

typedef __bf16 bf16_t;
typedef __bf16 bf16x8 __attribute__((ext_vector_type(8)));
typedef __bf16 bf16x4 __attribute__((ext_vector_type(4)));
typedef float f32x4 __attribute__((ext_vector_type(4)));

#define HH 96
#define WW 96
#define CC 128
#define HEADS 4
#define HD 32
#define TOK (HH * WW)      // 9216
#define PLANE (TOK * CC)   // 1179648 elements
#define KW 7
#define KK 49

// weight slab offsets (bf16 elements) inside ws
#define W_QKV 0
#define W_PROJ 49152
#define W_FC1 65536
#define W_FC2 131072
#define W_TOT 196608

// fp32 -> bf16x8 (two float4 loads + cvt)
__device__ __forceinline__ bf16x8 cvt8(const float* __restrict__ p) {
    const f32x4 a = *(const f32x4*)p;
    const f32x4 b = *(const f32x4*)(p + 4);
    bf16x8 r;
    r[0] = (bf16_t)a[0]; r[1] = (bf16_t)a[1]; r[2] = (bf16_t)a[2]; r[3] = (bf16_t)a[3];
    r[4] = (bf16_t)b[0]; r[5] = (bf16_t)b[1]; r[6] = (bf16_t)b[2]; r[7] = (bf16_t)b[3];
    return r;
}

// ---------------------------------------------------------------------------
// NT-tile MFMA strip: C[m][n] += sum_k A[m][k]*W[n][k]; A,W at tile origin.
// A-frag: lane holds A[lane&15][(lane>>4)*8+j]; B-frag: W[t*16+(lane&15)][...]
// C/D: reg r -> row (lane>>4)*4+r, col t*16+(lane&15)
// ---------------------------------------------------------------------------
template <int NT>
__device__ __forceinline__ void mmaN(const bf16_t* __restrict__ A, int lda,
                                     const bf16_t* __restrict__ W, int ldb,
                                     int K, f32x4* acc) {
    const int lane = threadIdx.x & 63;
    const bf16_t* ap = A + (lane & 15) * lda + ((lane >> 4) * 8);
    const bf16_t* bp = W + (lane & 15) * ldb + ((lane >> 4) * 8);
    for (int k0 = 0; k0 < K; k0 += 32) {
        bf16x8 a = *(const bf16x8*)(ap + k0);
#pragma unroll
        for (int t = 0; t < NT; t++) {
            bf16x8 b = *(const bf16x8*)(bp + t * 16 * ldb + k0);
            acc[t] = __builtin_amdgcn_mfma_f32_16x16x32_bf16(a, b, acc[t], 0, 0, 0);
        }
    }
}

// K0: convert the 4 fp32 weight matrices to one bf16 slab in ws.
__global__ __launch_bounds__(256) void k_cvt(const float* __restrict__ qkv_w,
                                             const float* __restrict__ proj_w,
                                             const float* __restrict__ fc1_w,
                                             const float* __restrict__ fc2_w,
                                             bf16_t* __restrict__ wb) {
    const int base = (blockIdx.x * 256 + threadIdx.x) * 4;
    const float* src;
    if (base < W_PROJ)      src = qkv_w + base;
    else if (base < W_FC1)  src = proj_w + (base - W_PROJ);
    else if (base < W_FC2)  src = fc1_w + (base - W_FC1);
    else                    src = fc2_w + (base - W_FC2);
    const f32x4 a = *(const f32x4*)src;
    bf16x4 r;
    r[0] = (bf16_t)a[0]; r[1] = (bf16_t)a[1]; r[2] = (bf16_t)a[2]; r[3] = (bf16_t)a[3];
    *(bf16x4*)(wb + base) = r;
}

// K1: qkv = x @ qkv_w.T + qkv_b. x fp32 (inline cvt); q/k/v bf16 [tok][128].
__global__ __launch_bounds__(256) void k_qkv(const float* __restrict__ x,
                                             const bf16_t* __restrict__ wb,
                                             const float* __restrict__ bias,
                                             bf16_t* __restrict__ q,
                                             bf16_t* __restrict__ k,
                                             bf16_t* __restrict__ v) {
    const int wid = blockIdx.x * 4 + (threadIdx.x >> 6);   // 3456 waves
    const int m0 = (wid / 6) * 16;
    const int n0 = (wid % 6) * 64;
    const int lane = threadIdx.x & 63;
    const float* ap = x + (m0 + (lane & 15)) * CC + ((lane >> 4) * 8);
    const bf16_t* bp = wb + (n0 + (lane & 15)) * CC + ((lane >> 4) * 8);
    f32x4 acc[4] = {};
    for (int k0 = 0; k0 < CC; k0 += 32) {
        bf16x8 a = cvt8(ap + k0);
#pragma unroll
        for (int t = 0; t < 4; t++) {
            bf16x8 b = *(const bf16x8*)(bp + t * 16 * CC + k0);
            acc[t] = __builtin_amdgcn_mfma_f32_16x16x32_bf16(a, b, acc[t], 0, 0, 0);
        }
    }
#pragma unroll
    for (int t = 0; t < 4; t++) {
        const int n = n0 + t * 16 + (lane & 15);
        const float bb = bias[n];
        const int part = n >> 7;           // 0=q 1=k 2=v
        const int c = n & 127;
        bf16_t* dst = (part == 0) ? q : (part == 1) ? k : v;
#pragma unroll
        for (int r = 0; r < 4; r++) {
            const int m = m0 + (lane >> 4) * 4 + r;
            dst[m * CC + c] = (bf16_t)(acc[t][r] + bb);
        }
    }
}

// K2: neighborhood attention via MFMA. Block = 4x4 token tile (576 blocks),
// one wave per head. Phase 1: logits[16 tok][112 patch] = Q @ K_patch^T via
// 7 mfma_16x16x32 (K=32=head dim), mask to the clipped 7x7 window, register
// softmax. Phase 2: O[16][32] = P[16][128] @ V^T via 8 mfma (V transpose-
// staged into LDS, reusing the ks/qs region after a barrier).
#define PATCH 10
#define PSZ 100
#define NPAD 112            // 7 N-tiles of 16
#define STR 136             // LDS row stride (bf16): 272B = 68 banks -> 2-way
__global__ __launch_bounds__(256) void k_na2d(bf16_t* __restrict__ qo,
                                              const bf16_t* __restrict__ kg,
                                              const bf16_t* __restrict__ vg) {
    // region A: phase1 = ks[112][STR] + qs[16][STR]; phase2 = vst[128][STR]
    __shared__ __align__(16) bf16_t regA[(NPAD + 16) * STR];  // 34816 B
    __shared__ __align__(16) bf16_t Pbuf[4 * 16 * STR];       // 17408 B
    bf16_t* ks  = regA;
    bf16_t* qs  = regA + NPAD * STR;
    bf16_t* vst = regA;                 // overlaps ks/qs (after barrier)

    const int tid = threadIdx.x;
    const int w = tid >> 6, lane = tid & 63;
    const int g = lane >> 4, li = lane & 15;
    const int bi = blockIdx.x / 24, bj = blockIdx.x % 24;
    const int i0 = bi * 4, j0 = bj * 4;
    const int pr0 = min(max(i0 - 3, 0), HH - PATCH);
    const int pc0 = min(max(j0 - 3, 0), WW - PATCH);

    // ---- stage K patch rows 0..99 (rows 100..111 garbage -> masked) ----
    for (int idx = tid; idx < PSZ * 16; idx += 256) {
        const int row = idx >> 4, c8 = idx & 15;
        const int pi = row / PATCH, pj = row - PATCH * pi;
        *(bf16x8*)(ks + row * STR + c8 * 8) =
            *(const bf16x8*)(kg + ((pr0 + pi) * WW + (pc0 + pj)) * CC + c8 * 8);
    }
    {   // stage Q rows: 16 tokens x 16 chunks (one per thread)
        const int row = tid >> 4, c8 = tid & 15;
        const int ti = row >> 2, tj = row & 3;
        *(bf16x8*)(qs + row * STR + c8 * 8) =
            *(const bf16x8*)(qo + ((i0 + ti) * WW + (j0 + tj)) * CC + c8 * 8);
    }
    __syncthreads();

    const int head = w;
    // ---- phase 1: 7 MFMA -> logits[16][112] ----
    f32x4 lg[7];
    {
        const bf16x8 aq = *(const bf16x8*)(qs + li * STR + head * HD + g * 8);
#pragma unroll
        for (int t = 0; t < 7; t++) {
            const bf16x8 bk = *(const bf16x8*)(ks + (t * 16 + li) * STR + head * HD + g * 8);
            lg[t] = __builtin_amdgcn_mfma_f32_16x16x32_bf16(aq, bk, (f32x4){0.f,0.f,0.f,0.f}, 0, 0, 0);
        }
    }

    // ---- mask + softmax (row m = g*4+r, cols t*16+li) ----
    int lr[4], lc[4];
#pragma unroll
    for (int r = 0; r < 4; r++) {
        const int m = g * 4 + r;
        const int i = i0 + (m >> 2), j = j0 + (m & 3);
        lr[r] = min(max(i - 3, 0), HH - KW) - pr0;
        lc[r] = min(max(j - 3, 0), WW - KW) - pc0;
    }
    const float scale = 0.17677669529663687f;   // 1/sqrt(32)
#pragma unroll
    for (int t = 0; t < 7; t++) {
        const int col = t * 16 + li;
        const int pi = col / PATCH, pj = col - PATCH * pi;
#pragma unroll
        for (int r = 0; r < 4; r++) {
            const bool valid = (col < PSZ) &&
                               ((unsigned)(pi - lr[r]) <= 6u) &&
                               ((unsigned)(pj - lc[r]) <= 6u);
            lg[t][r] = valid ? lg[t][r] * scale : -1e30f;   // select: NaN-safe
        }
    }
    f32x4 mx = lg[0], sm;
#pragma unroll
    for (int t = 1; t < 7; t++)
#pragma unroll
        for (int r = 0; r < 4; r++) mx[r] = fmaxf(mx[r], lg[t][r]);
#pragma unroll
    for (int off = 8; off; off >>= 1)
#pragma unroll
        for (int r = 0; r < 4; r++) mx[r] = fmaxf(mx[r], __shfl_xor(mx[r], off));
#pragma unroll
    for (int r = 0; r < 4; r++) sm[r] = 0.f;
#pragma unroll
    for (int t = 0; t < 7; t++)
#pragma unroll
        for (int r = 0; r < 4; r++) {
            lg[t][r] = __expf(lg[t][r] - mx[r]);   // -1e30 -> exp -> 0
            sm[r] += lg[t][r];
        }
#pragma unroll
    for (int off = 8; off; off >>= 1)
#pragma unroll
        for (int r = 0; r < 4; r++) sm[r] += __shfl_xor(sm[r], off);
#pragma unroll
    for (int r = 0; r < 4; r++) sm[r] = 1.f / sm[r];

    // ---- write P (bf16) to per-wave LDS; zero cols 112..127 ----
    bf16_t* Pw = Pbuf + w * 16 * STR;
#pragma unroll
    for (int t = 0; t < 7; t++)
#pragma unroll
        for (int r = 0; r < 4; r++)
            Pw[(g * 4 + r) * STR + t * 16 + li] = (bf16_t)(lg[t][r] * sm[r]);
    *(bf16x4*)(Pw + (lane >> 2) * STR + NPAD + (lane & 3) * 4) = (bf16x4){0,0,0,0};

    __syncthreads();
    // ---- transpose-stage V into vst[ch][patch] (overwrites ks/qs) ----
    for (int idx = tid; idx < PSZ * 16; idx += 256) {
        const int c8 = idx / PSZ;              // channel/8
        const int p  = idx - c8 * PSZ;         // patch 0..99 (lane-fastest)
        const int pi = p / PATCH, pj = p - PATCH * pi;
        const bf16x8 t = *(const bf16x8*)(vg + ((pr0 + pi) * WW + (pc0 + pj)) * CC + c8 * 8);
#pragma unroll
        for (int e = 0; e < 8; e++) vst[(c8 * 8 + e) * STR + p] = t[e];
    }
    // zero vst patch cols 100..131 (0 * NaN = NaN in MFMA otherwise)
    for (int idx = tid; idx < 128 * 8; idx += 256) {
        const int row = idx >> 3, c4 = idx & 7;
        *(bf16x4*)(vst + row * STR + PSZ + c4 * 4) = (bf16x4){0,0,0,0};
    }
    __syncthreads();

    // ---- phase 2: O = P @ V^T, 8 MFMA (K=128) ----
    f32x4 oA[2] = {};
#pragma unroll
    for (int ks0 = 0; ks0 < 128; ks0 += 32) {
        const bf16x8 a = *(const bf16x8*)(Pw + li * STR + ks0 + g * 8);
#pragma unroll
        for (int t2 = 0; t2 < 2; t2++) {
            const bf16x8 b = *(const bf16x8*)(vst + (head * HD + t2 * 16 + li) * STR + ks0 + g * 8);
            oA[t2] = __builtin_amdgcn_mfma_f32_16x16x32_bf16(a, b, oA[t2], 0, 0, 0);
        }
    }
#pragma unroll
    for (int t2 = 0; t2 < 2; t2++)
#pragma unroll
        for (int r = 0; r < 4; r++) {
            const int m = g * 4 + r;
            const int i = i0 + (m >> 2), j = j0 + (m & 3);
            qo[(i * WW + j) * CC + head * HD + t2 * 16 + li] = (bf16_t)oA[t2][r];
        }
}

// K3: x0 = o @ proj_w.T + proj_b  (o bf16 in d_out; x0 bf16 -> dead k plane)
__global__ __launch_bounds__(256) void k_proj(const bf16_t* __restrict__ o,
                                              const bf16_t* __restrict__ wb,
                                              const float* __restrict__ bias,
                                              bf16_t* __restrict__ x0) {
    const int wid = blockIdx.x * 4 + (threadIdx.x >> 6);   // 1152 waves
    const int m0 = (wid / 2) * 16;
    const int n0 = (wid % 2) * 64;
    f32x4 acc[4] = {};
    mmaN<4>(o + m0 * CC, CC, wb + n0 * CC, CC, CC, acc);
    const int lane = threadIdx.x & 63;
#pragma unroll
    for (int t = 0; t < 4; t++) {
        const int n = n0 + t * 16 + (lane & 15);
        const float bb = bias[n];
#pragma unroll
        for (int r = 0; r < 4; r++) {
            const int m = m0 + (lane >> 4) * 4 + r;
            x0[m * CC + n] = (bf16_t)(acc[t][r] + bb);
        }
    }
}

// K4: fused MLP: out = gelu(x0 @ fc1_w.T + fc1_b) @ fc2_w.T + fc2_b.
// 16 rows/block; h1 [16][512] bf16 in LDS (stride 520). out is FP32.
// gelu: tanh form via one __expf (err < bf16 quantization of h1).
#define H1S 520
__global__ __launch_bounds__(256) void k_mlp(const bf16_t* __restrict__ x0,
                                             const bf16_t* __restrict__ w1,
                                             const float* __restrict__ b1,
                                             const bf16_t* __restrict__ w2,
                                             const float* __restrict__ b2,
                                             float* __restrict__ out) {
    __shared__ __align__(16) bf16_t h1s[16 * H1S];
    const int wv = threadIdx.x >> 6;
    const int lane = threadIdx.x & 63;
    const int m0 = blockIdx.x * 16;

    {   // stage 1: wave wv -> h1 cols [wv*128, wv*128+128)
        f32x4 acc[8] = {};
        mmaN<8>(x0 + m0 * CC, CC, w1 + (wv * 128) * CC, CC, CC, acc);
#pragma unroll
        for (int t = 0; t < 8; t++) {
            const int n = wv * 128 + t * 16 + (lane & 15);
            const float bb = b1[n];
#pragma unroll
            for (int r = 0; r < 4; r++) {
                const int m = (lane >> 4) * 4 + r;
                const float xv = acc[t][r] + bb;
                const float u = 0.7978845608028654f * (xv + 0.044715f * xv * xv * xv);
                const float e = __expf(2.f * u);
                const float gg = 0.5f * xv * (2.f - 2.f / (e + 1.f));
                h1s[m * H1S + n] = (bf16_t)gg;
            }
        }
    }
    __syncthreads();

    {   // stage 2: wave wv -> out cols [wv*32, wv*32+32), K=512 from LDS
        f32x4 acc[2] = {};
        mmaN<2>(h1s, H1S, w2 + (wv * 32) * (4 * CC), 4 * CC, 4 * CC, acc);
#pragma unroll
        for (int t = 0; t < 2; t++) {
            const int n = wv * 32 + t * 16 + (lane & 15);
            const float bb = b2[n];
#pragma unroll
            for (int r = 0; r < 4; r++) {
                const int m = (lane >> 4) * 4 + r;
                float xv = acc[t][r] + bb;
                xv = fminf(fmaxf(xv, -1e4f), 1e4f);   // diagnostic clamp
                out[(m0 + m) * CC + n] = xv;
            }
        }
    }
}

extern "C" void kernel_launch(void* const* d_in, const int* in_sizes, int n_in,
                              void* d_out, int out_size, void* d_ws, size_t ws_size,
                              hipStream_t stream) {
    const float* x      = (const float*)d_in[0];
    const float* qkv_w  = (const float*)d_in[1];
    const float* qkv_b  = (const float*)d_in[2];
    const float* proj_w = (const float*)d_in[3];
    const float* proj_b = (const float*)d_in[4];
    const float* fc1_w  = (const float*)d_in[5];
    const float* fc1_b  = (const float*)d_in[6];
    const float* fc2_w  = (const float*)d_in[7];
    const float* fc2_b  = (const float*)d_in[8];

    // d_out (fp32-sized, 4.5 MB) doubles as bf16 scratch for q then o; the
    // final k_mlp overwrites it with the fp32 result.
    bf16_t* qo = (bf16_t*)d_out;
    bf16_t* ws = (bf16_t*)d_ws;
    bf16_t* kb = ws;                  // [9216][128] bf16
    bf16_t* vb = ws + PLANE;          // [9216][128] bf16
    bf16_t* wb = ws + 2 * PLANE;      // 196608 bf16 weight slab
    bf16_t* x0 = kb;                  // k plane dead after attention
    // total ws: 2*PLANE + W_TOT bf16 = 4.9 MB

    k_cvt <<<192,  256, 0, stream>>>(qkv_w, proj_w, fc1_w, fc2_w, wb);
    k_qkv <<<864,  256, 0, stream>>>(x, wb + W_QKV, qkv_b, qo, kb, vb);
    k_na2d<<<576,  256, 0, stream>>>(qo, kb, vb);
    k_proj<<<288,  256, 0, stream>>>(qo, wb + W_PROJ, proj_b, x0);
    k_mlp <<<576,  256, 0, stream>>>(x0, wb + W_FC1, fc1_b, wb + W_FC2, fc2_b,
                                     (float*)d_out);
}

// Round 8
// 129.342 us; speedup vs baseline: 1.3116x; 1.0117x over previous
//
#include <hip/hip_runtime.h>

typedef __bf16 bf16_t;
typedef __bf16 bf16x8 __attribute__((ext_vector_type(8)));
typedef __bf16 bf16x4 __attribute__((ext_vector_type(4)));
typedef float f32x4 __attribute__((ext_vector_type(4)));

#define HH 96
#define WW 96
#define CC 128
#define HEADS 4
#define HD 32
#define TOK (HH * WW)      // 9216
#define PLANE (TOK * CC)   // elements per bf16 [tok][128] plane
#define KW 7

// bf16 weight slab offsets (elements) in ws: proj, fc1, fc2
#define W_PROJ 0
#define W_FC1  16384
#define W_FC2  81920
#define W_TOT  147456

// na2d tile geometry
#define PATCH 10
#define PSZ 100
#define NPAD 112            // 7 N-tiles of 16
#define STR 136             // LDS row stride (bf16)
#define H1S 520             // mlp h1 LDS stride

// LDS: regA = ks[112][STR]+qs[16][STR] -> vst[128][STR] -> h1s[16][520]
//      Pbuf = P[4][16][STR]            -> o_s[16][STR] + x0s[16][STR]
#define REGA_ELE ((NPAD + 16) * STR)        // 17408 bf16
#define PBUF_ELE (4 * 16 * STR)             // 8704 bf16
#define SMEM_BYTES ((REGA_ELE + PBUF_ELE) * 2)   // 52224 B

// fp32 -> bf16x8 (two float4 loads + cvt)
__device__ __forceinline__ bf16x8 cvt8(const float* __restrict__ p) {
    const f32x4 a = *(const f32x4*)p;
    const f32x4 b = *(const f32x4*)(p + 4);
    bf16x8 r;
    r[0] = (bf16_t)a[0]; r[1] = (bf16_t)a[1]; r[2] = (bf16_t)a[2]; r[3] = (bf16_t)a[3];
    r[4] = (bf16_t)b[0]; r[5] = (bf16_t)b[1]; r[6] = (bf16_t)b[2]; r[7] = (bf16_t)b[3];
    return r;
}

// NT-tile MFMA strip, bf16 A (lda) x bf16 W (ldb), at tile origin.
// A-frag: lane holds A[lane&15][(lane>>4)*8+j]; B-frag: W[t*16+(lane&15)][...]
// C/D: reg r -> row (lane>>4)*4+r, col t*16+(lane&15)
template <int NT>
__device__ __forceinline__ void mmaN(const bf16_t* __restrict__ A, int lda,
                                     const bf16_t* __restrict__ W, int ldb,
                                     int K, f32x4* acc) {
    const int lane = threadIdx.x & 63;
    const bf16_t* ap = A + (lane & 15) * lda + ((lane >> 4) * 8);
    const bf16_t* bp = W + (lane & 15) * ldb + ((lane >> 4) * 8);
    for (int k0 = 0; k0 < K; k0 += 32) {
        bf16x8 a = *(const bf16x8*)(ap + k0);
#pragma unroll
        for (int t = 0; t < NT; t++) {
            bf16x8 b = *(const bf16x8*)(bp + t * 16 * ldb + k0);
            acc[t] = __builtin_amdgcn_mfma_f32_16x16x32_bf16(a, b, acc[t], 0, 0, 0);
        }
    }
}

// ===========================================================================
// Kernel A: weight slab cvt + qkv GEMM. 576 blocks x 256.
// q -> d_out as FP32 [tok][128]; k/v -> ws bf16 [tok][128].
// ===========================================================================
__global__ __launch_bounds__(256) void k_qkv(const float* __restrict__ x,
                                             const float* __restrict__ qkv_w,
                                             const float* __restrict__ qkv_b,
                                             const float* __restrict__ proj_w,
                                             const float* __restrict__ fc1_w,
                                             const float* __restrict__ fc2_w,
                                             float* __restrict__ qf,
                                             bf16_t* __restrict__ kb,
                                             bf16_t* __restrict__ vb,
                                             bf16_t* __restrict__ wb) {
    const int tid = threadIdx.x, bid = blockIdx.x;
    // ---- cvt proj/fc1/fc2 -> bf16 slab (147456 elems, 36864 x4 chunks) ----
    {
        const int idx = bid * 256 + tid;
        if (idx < W_TOT / 4) {
            const int base = idx * 4;
            const float* src;
            if (base < W_FC1)      src = proj_w + base;
            else if (base < W_FC2) src = fc1_w + (base - W_FC1);
            else                   src = fc2_w + (base - W_FC2);
            const f32x4 a = *(const f32x4*)src;
            bf16x4 r;
            r[0] = (bf16_t)a[0]; r[1] = (bf16_t)a[1];
            r[2] = (bf16_t)a[2]; r[3] = (bf16_t)a[3];
            *(bf16x4*)(wb + base) = r;
        }
    }
    // ---- qkv GEMM: block = 16 tokens, wave w = cols w*96..w*96+95 ----
    const int w = tid >> 6, lane = tid & 63;
    const int g = lane >> 4, li = lane & 15;
    const int m0 = bid * 16;
    const float* ap = x + (m0 + li) * CC + g * 8;
    const float* bp = qkv_w + (w * 96 + li) * CC + g * 8;
    f32x4 acc[6] = {};
    for (int k0 = 0; k0 < CC; k0 += 32) {
        bf16x8 a = cvt8(ap + k0);
#pragma unroll
        for (int t = 0; t < 6; t++) {
            bf16x8 b = cvt8(bp + t * 16 * CC + k0);
            acc[t] = __builtin_amdgcn_mfma_f32_16x16x32_bf16(a, b, acc[t], 0, 0, 0);
        }
    }
#pragma unroll
    for (int t = 0; t < 6; t++) {
        const int n = w * 96 + t * 16 + li;
        const float bb = qkv_b[n];
        const int part = n >> 7, c = n & 127;
#pragma unroll
        for (int r = 0; r < 4; r++) {
            const int m = m0 + g * 4 + r;
            const float val = acc[t][r] + bb;
            if (part == 0)      qf[m * CC + c] = val;          // q fp32
            else if (part == 1) kb[m * CC + c] = (bf16_t)val;
            else                vb[m * CC + c] = (bf16_t)val;
        }
    }
}

// ===========================================================================
// Kernel B: na2d + proj + mlp, fused per 4x4-token tile. 576 blocks x 256.
// Reads q fp32 (own tile) from d_out, k/v bf16 (neighbors) from ws, writes
// final fp32 out over its OWN q rows in d_out (row-exact overwrite).
// ===========================================================================
__global__ __launch_bounds__(256, 3) void k_attn_mlp(
        float* __restrict__ qof,            // d_out fp32 [tok][128]
        const bf16_t* __restrict__ kg,
        const bf16_t* __restrict__ vg,
        const bf16_t* __restrict__ wb,
        const float* __restrict__ proj_b,
        const float* __restrict__ fc1_b,
        const float* __restrict__ fc2_b) {
    __shared__ __align__(16) bf16_t smem[REGA_ELE + PBUF_ELE];
    bf16_t* ks   = smem;
    bf16_t* qs   = smem + NPAD * STR;
    bf16_t* vst  = smem;                    // reuse after sync
    bf16_t* h1s  = smem;                    // reuse after sync
    bf16_t* Pbuf = smem + REGA_ELE;
    bf16_t* o_s  = Pbuf;                    // reuse after sync
    bf16_t* x0s  = Pbuf + 16 * STR;

    const int tid = threadIdx.x;
    const int w = tid >> 6, lane = tid & 63;
    const int g = lane >> 4, li = lane & 15;
    const int bid = blockIdx.x;
    const int bi = bid / 24, bj = bid % 24;
    const int i0 = bi * 4, j0 = bj * 4;
    const int pr0 = min(max(i0 - 3, 0), HH - PATCH);
    const int pc0 = min(max(j0 - 3, 0), WW - PATCH);
    const int head = w;

    // ---- stage K patch (rows 100..111 garbage -> masked) + q tile ----
    for (int idx = tid; idx < PSZ * 16; idx += 256) {
        const int row = idx >> 4, c8 = idx & 15;
        const int pi = row / PATCH, pj = row - PATCH * pi;
        *(bf16x8*)(ks + row * STR + c8 * 8) =
            *(const bf16x8*)(kg + ((pr0 + pi) * WW + (pc0 + pj)) * CC + c8 * 8);
    }
    {
        const int row = tid >> 4, c8 = tid & 15;
        const int ti = row >> 2, tj = row & 3;
        *(bf16x8*)(qs + row * STR + c8 * 8) =
            cvt8(qof + ((i0 + ti) * WW + (j0 + tj)) * CC + c8 * 8);
    }
    __syncthreads();

    // ---- phase 1: logits[16][112] = Q @ K^T, 7 MFMA ----
    f32x4 lg[7];
    {
        const bf16x8 aq = *(const bf16x8*)(qs + li * STR + head * HD + g * 8);
#pragma unroll
        for (int t = 0; t < 7; t++) {
            const bf16x8 bk = *(const bf16x8*)(ks + (t * 16 + li) * STR + head * HD + g * 8);
            lg[t] = __builtin_amdgcn_mfma_f32_16x16x32_bf16(aq, bk, (f32x4){0.f,0.f,0.f,0.f}, 0, 0, 0);
        }
    }
    // ---- mask + register softmax ----
    int lr[4], lc[4];
#pragma unroll
    for (int r = 0; r < 4; r++) {
        const int m = g * 4 + r;
        const int i = i0 + (m >> 2), j = j0 + (m & 3);
        lr[r] = min(max(i - 3, 0), HH - KW) - pr0;
        lc[r] = min(max(j - 3, 0), WW - KW) - pc0;
    }
    const float scale = 0.17677669529663687f;   // 1/sqrt(32)
#pragma unroll
    for (int t = 0; t < 7; t++) {
        const int col = t * 16 + li;
        const int pi = col / PATCH, pj = col - PATCH * pi;
#pragma unroll
        for (int r = 0; r < 4; r++) {
            const bool valid = (col < PSZ) &&
                               ((unsigned)(pi - lr[r]) <= 6u) &&
                               ((unsigned)(pj - lc[r]) <= 6u);
            lg[t][r] = valid ? lg[t][r] * scale : -1e30f;   // select: NaN-safe
        }
    }
    f32x4 mx = lg[0], sm;
#pragma unroll
    for (int t = 1; t < 7; t++)
#pragma unroll
        for (int r = 0; r < 4; r++) mx[r] = fmaxf(mx[r], lg[t][r]);
#pragma unroll
    for (int off = 8; off; off >>= 1)
#pragma unroll
        for (int r = 0; r < 4; r++) mx[r] = fmaxf(mx[r], __shfl_xor(mx[r], off));
#pragma unroll
    for (int r = 0; r < 4; r++) sm[r] = 0.f;
#pragma unroll
    for (int t = 0; t < 7; t++)
#pragma unroll
        for (int r = 0; r < 4; r++) {
            lg[t][r] = __expf(lg[t][r] - mx[r]);
            sm[r] += lg[t][r];
        }
#pragma unroll
    for (int off = 8; off; off >>= 1)
#pragma unroll
        for (int r = 0; r < 4; r++) sm[r] += __shfl_xor(sm[r], off);
#pragma unroll
    for (int r = 0; r < 4; r++) sm[r] = 1.f / sm[r];

    // ---- write P bf16 (zero cols 112..127) ----
    bf16_t* Pw = Pbuf + w * 16 * STR;
#pragma unroll
    for (int t = 0; t < 7; t++)
#pragma unroll
        for (int r = 0; r < 4; r++)
            Pw[(g * 4 + r) * STR + t * 16 + li] = (bf16_t)(lg[t][r] * sm[r]);
    *(bf16x4*)(Pw + (lane >> 2) * STR + NPAD + (lane & 3) * 4) = (bf16x4){0,0,0,0};
    __syncthreads();   // everyone done with ks/qs; P visible

    // ---- transpose-stage V into vst[ch][patch]; zero cols 100..131 ----
    for (int idx = tid; idx < PSZ * 16; idx += 256) {
        const int c8 = idx / PSZ, p = idx - c8 * PSZ;
        const int pi = p / PATCH, pj = p - PATCH * pi;
        const bf16x8 t = *(const bf16x8*)(vg + ((pr0 + pi) * WW + (pc0 + pj)) * CC + c8 * 8);
#pragma unroll
        for (int e = 0; e < 8; e++) vst[(c8 * 8 + e) * STR + p] = t[e];
    }
    for (int idx = tid; idx < 128 * 8; idx += 256) {
        const int row = idx >> 3, c4 = idx & 7;
        *(bf16x4*)(vst + row * STR + PSZ + c4 * 4) = (bf16x4){0,0,0,0};
    }
    __syncthreads();

    // ---- phase 2: O = P @ V^T, 8 MFMA (K=128) ----
    f32x4 oA[2] = {};
#pragma unroll
    for (int ks0 = 0; ks0 < 128; ks0 += 32) {
        const bf16x8 a = *(const bf16x8*)(Pw + li * STR + ks0 + g * 8);
#pragma unroll
        for (int t2 = 0; t2 < 2; t2++) {
            const bf16x8 b = *(const bf16x8*)(vst + (head * HD + t2 * 16 + li) * STR + ks0 + g * 8);
            oA[t2] = __builtin_amdgcn_mfma_f32_16x16x32_bf16(a, b, oA[t2], 0, 0, 0);
        }
    }
    __syncthreads();   // done reading Pbuf/vst

    // ---- o -> LDS (o_s[16][STR], cols head*32..head*32+31) ----
#pragma unroll
    for (int t2 = 0; t2 < 2; t2++)
#pragma unroll
        for (int r = 0; r < 4; r++)
            o_s[(g * 4 + r) * STR + head * HD + t2 * 16 + li] = (bf16_t)oA[t2][r];
    __syncthreads();

    // ---- proj: x0[16][128] = o @ proj_w^T + b; wave w -> cols w*32.. ----
    {
        f32x4 acc[2] = {};
        mmaN<2>(o_s, STR, wb + W_PROJ + (w * 32) * CC, CC, CC, acc);
#pragma unroll
        for (int t = 0; t < 2; t++) {
            const int n = w * 32 + t * 16 + li;
            const float bb = proj_b[n];
#pragma unroll
            for (int r = 0; r < 4; r++)
                x0s[(g * 4 + r) * STR + n] = (bf16_t)(acc[t][r] + bb);
        }
    }
    __syncthreads();

    // ---- mlp stage 1: h1 = gelu(x0 @ fc1^T + b1); wave w -> cols w*128 ----
    {
        f32x4 acc[8] = {};
        mmaN<8>(x0s, STR, wb + W_FC1 + (w * 128) * CC, CC, CC, acc);
#pragma unroll
        for (int t = 0; t < 8; t++) {
            const int n = w * 128 + t * 16 + li;
            const float bb = fc1_b[n];
#pragma unroll
            for (int r = 0; r < 4; r++) {
                const int m = g * 4 + r;
                const float xv = acc[t][r] + bb;
                const float u = 0.7978845608028654f * (xv + 0.044715f * xv * xv * xv);
                const float e = __expf(2.f * u);
                const float gg = 0.5f * xv * (2.f - 2.f / (e + 1.f));
                h1s[m * H1S + n] = (bf16_t)gg;
            }
        }
    }
    __syncthreads();

    // ---- mlp stage 2: out = h1 @ fc2^T + b2 (fp32, over own q rows) ----
    {
        f32x4 acc[2] = {};
        mmaN<2>(h1s, H1S, wb + W_FC2 + (w * 32) * (4 * CC), 4 * CC, 4 * CC, acc);
#pragma unroll
        for (int t = 0; t < 2; t++) {
            const int n = w * 32 + t * 16 + li;
            const float bb = fc2_b[n];
#pragma unroll
            for (int r = 0; r < 4; r++) {
                const int m = g * 4 + r;
                const int i = i0 + (m >> 2), j = j0 + (m & 3);
                float xv = acc[t][r] + bb;
                xv = fminf(fmaxf(xv, -1e4f), 1e4f);   // diagnostic clamp
                qof[(i * WW + j) * CC + n] = xv;
            }
        }
    }
}

extern "C" void kernel_launch(void* const* d_in, const int* in_sizes, int n_in,
                              void* d_out, int out_size, void* d_ws, size_t ws_size,
                              hipStream_t stream) {
    const float* x      = (const float*)d_in[0];
    const float* qkv_w  = (const float*)d_in[1];
    const float* qkv_b  = (const float*)d_in[2];
    const float* proj_w = (const float*)d_in[3];
    const float* proj_b = (const float*)d_in[4];
    const float* fc1_w  = (const float*)d_in[5];
    const float* fc1_b  = (const float*)d_in[6];
    const float* fc2_w  = (const float*)d_in[7];
    const float* fc2_b  = (const float*)d_in[8];

    float* qof = (float*)d_out;         // q fp32 -> final fp32 out (in place)
    bf16_t* ws = (bf16_t*)d_ws;
    bf16_t* kb = ws;                    // [9216][128] bf16
    bf16_t* vb = ws + PLANE;            // [9216][128] bf16
    bf16_t* wb = ws + 2 * PLANE;        // 147456-elem bf16 weight slab
    // ws total: 2*PLANE*2 + 147456*2 = 5.01 MB

    k_qkv     <<<576, 256, 0, stream>>>(x, qkv_w, qkv_b, proj_w, fc1_w, fc2_w,
                                        qof, kb, vb, wb);
    k_attn_mlp<<<576, 256, 0, stream>>>(qof, kb, vb, wb, proj_b, fc1_b, fc2_b);
}